// Round 14
// baseline (184.247 us; speedup 1.0000x reference)
//
#include <hip/hip_runtime.h>
#include <hip/hip_bf16.h>
#include <math.h>

#define NN 4096
#define DD 128

typedef __attribute__((ext_vector_type(8))) short bf16x8;
typedef __attribute__((ext_vector_type(4))) float f32x4;
#define AS3 __attribute__((address_space(3)))

// ws layout (doubles): gemm-loss slots ws[k*8], k=0..15; ws[128]=bqc1,
// ws[129]=bqc2, ws[130]=fdc.

__device__ __forceinline__ void gload_lds16(const float* g, float* l) {
    __builtin_amdgcn_global_load_lds((const __attribute__((address_space(1))) char*)g,
                                     (AS3 char*)l, 16, 0, 0);
}

// ---- fused prep: convert F (f32 [d][i]) -> bf16 [i][d]  +  bqc partials ----
__global__ __launch_bounds__(256)
void convert_bqc_kernel(const float* __restrict__ FP, const float* __restrict__ FM,
                        const float* __restrict__ B,
                        __hip_bfloat16* __restrict__ FPt, __hip_bfloat16* __restrict__ FMt,
                        double* __restrict__ ws)
{
    const int y = blockIdx.y;
    const float* src = y ? FM : FP;
    __hip_bfloat16* dst = y ? FMt : FPt;
    const int t  = threadIdx.x;
    const int il = t & 127;
    const int dh = t >> 7;
    const int i  = blockIdx.x * 128 + il;
    float s = 0.f;
    #pragma unroll
    for (int it = 0; it < 8; ++it) {
        const int d0 = dh * 64 + it * 8;
        float a[8];
        #pragma unroll
        for (int j = 0; j < 8; ++j) {
            a[j] = src[(long)(d0 + j) * NN + i];
            const float b = B[(long)(d0 + j) * NN + i];
            const float d = a[j] - b;
            s += d * d;
        }
        union { __hip_bfloat162 h[4]; bf16x8 v; } p;
        #pragma unroll
        for (int j = 0; j < 4; ++j)
            p.h[j] = __float22bfloat162_rn(make_float2(a[2*j], a[2*j+1]));
        *(bf16x8*)&dst[(long)i * DD + d0] = p.v;
    }
    __shared__ float red[4];
    #pragma unroll
    for (int off = 32; off; off >>= 1) s += __shfl_down(s, off);
    if ((t & 63) == 0) red[t >> 6] = s;
    __syncthreads();
    if (t == 0)
        atomicAdd(&ws[128 + y], (double)(red[0] + red[1] + red[2] + red[3]));
}

// ---- producer/consumer fused gemm-loss ------------------------------------
// 768 blocks = z(3) x i-slab(256, 16 rows). 8 waves: wave 0-1 = PRODUCERS
// (pure S streamers: 16 x 1KB-contiguous gload_lds per 16KB buffer, depth-2
// per producer = 32KB outstanding/wave, no compute, no dependent stalls),
// waves 2-7 = CONSUMERS (spin on LDS flag; F from L2 + MFMA + log epilogue).
// Ring of 4 buffers (rows padded to 1040B); cross-wave sync via LDS flags.
__global__ __launch_bounds__(512, 4)
void gemm_loss_pc(const float* __restrict__ SU, const float* __restrict__ SP,
                  const float* __restrict__ SM,
                  const __hip_bfloat16* __restrict__ FPt_,
                  const __hip_bfloat16* __restrict__ FMt_,
                  double* __restrict__ accum)
{
    __shared__ char sbuf[4 * 16640];   // 4 slots x 16 rows x 1040B
    __shared__ int flags[16];          // buffer b data-ready
    __shared__ int done[16];           // buffer b consumed
    const int t    = threadIdx.x;
    const int lane = t & 63, wid = t >> 6;
    const int bid  = blockIdx.x;              // 0..767
    const int z    = bid >> 8;
    const int i0   = (bid & 255) << 4;
    const float* S  = (z == 0) ? SU : (z == 1) ? SP : SM;
    const short* Fi = (const short*)((z == 2) ? FMt_ : FPt_);   // i-side (A)
    const short* Fj = (const short*)((z == 1) ? FPt_ : FMt_);   // j-side (B)
    const float onep = (z == 0) ? 1.0f : 1.0f + 1e-8f;

    if (t < 16) { flags[t] = 0; done[t] = 0; }
    __syncthreads();
    volatile int* vflags = (volatile int*)flags;
    volatile int* vdone  = (volatile int*)done;

    if (wid < 2) {
        // ======== PRODUCER (waves 0,1): buffers p, p+2, ..., p+14 ========
        const int p = wid;
#define ISSUEB(b_)                                                             \
        {                                                                      \
            const int slot_ = (b_) & 3;                                        \
            const float* gsrc = S + (long)i0 * NN + ((b_) << 8) + lane * 4;    \
            char* d0 = sbuf + slot_ * 16640;                                   \
            _Pragma("unroll")                                                  \
            for (int r_ = 0; r_ < 16; ++r_)                                    \
                gload_lds16(gsrc + (long)r_ * NN, (float*)(d0 + r_ * 1040));   \
        }
        ISSUEB(p);
        ISSUEB(p + 2);
        #pragma unroll 1
        for (int k = 0; k < 8; ++k) {
            const int b = p + 2 * k;
            if (k < 7) asm volatile("s_waitcnt vmcnt(16)" ::: "memory");
            else       asm volatile("s_waitcnt vmcnt(0)"  ::: "memory");
            if (lane == 0) vflags[b] = 1;
            if (k < 6) {
                // slot (b+4)&3 == b&3: wait until consumer finished buffer b
                while (vdone[b] == 0) __builtin_amdgcn_s_sleep(8);
                asm volatile("" ::: "memory");
                ISSUEB(b + 4);
            }
        }
#undef ISSUEB
    } else {
        // ======== CONSUMER (waves 2-7): buffers b with b%6 == wid-2 ========
        const int c   = wid - 2;
        const int l15 = lane & 15, l4 = lane >> 4;
        bf16x8 ai[4];
        #pragma unroll
        for (int kb = 0; kb < 4; ++kb)
            ai[kb] = *(const bf16x8*)&Fi[(long)(i0 + l15) * DD + kb * 32 + l4 * 8];

        float lsum = 0.f;
        #pragma unroll 1
        for (int b = c; b < 16; b += 6) {
            while (vflags[b] == 0) __builtin_amdgcn_s_sleep(8);
            asm volatile("" ::: "memory");
            const char* sb = sbuf + (b & 3) * 16640;
            const int j0 = b << 8;
            #pragma unroll 4
            for (int nf = 0; nf < 16; ++nf) {
                bf16x8 bj[4];
                #pragma unroll
                for (int kb = 0; kb < 4; ++kb)
                    bj[kb] = *(const bf16x8*)&Fj[(long)(j0 + nf * 16 + l15) * DD + kb * 32 + l4 * 8];
                f32x4 acc = {0.f, 0.f, 0.f, 0.f};
                #pragma unroll
                for (int kb = 0; kb < 4; ++kb)
                    acc = __builtin_amdgcn_mfma_f32_16x16x32_bf16(ai[kb], bj[kb], acc, 0, 0, 0);
                #pragma unroll
                for (int r = 0; r < 4; ++r) {
                    const float s = *(const float*)(sb + (l4 * 4 + r) * 1040 + (nf * 16 + l15) * 4);
                    const float o = 0.5f * acc[r];
                    lsum += fmaf(-s, o, __logf(o + onep));
                }
            }
            asm volatile("" ::: "memory");
            if (lane == 0) vdone[b] = 1;
        }
        float v = lsum;
        #pragma unroll
        for (int off = 32; off; off >>= 1) v += __shfl_down(v, off);
        if (lane == 0)
            atomicAdd(accum + ((bid & 15) << 3), (double)v);
    }
}

// ---------------- fallback path (round-2 kernel, used if ws too small) ------
__global__ __launch_bounds__(256, 2)
void gemm_loss_mfma(const float* __restrict__ S, const float* __restrict__ F1,
                    const float* __restrict__ F2, float eps, double* __restrict__ accum)
{
    __shared__ char lds[2][128 * 256];
    __shared__ float red[4];
    const int t  = threadIdx.x;
    const int i0 = blockIdx.y * 128;
    const int j0 = blockIdx.x * 128;
    {
        const int il   = t & 127;
        const int half = t >> 7;
        const float* c1 = F1 + i0 + il;
        const float* c2 = F2 + j0 + il;
        char* r1 = lds[0] + il * 256;
        char* r2 = lds[1] + il * 256;
        #pragma unroll
        for (int it = 0; it < 8; ++it) {
            const int q  = half * 8 + it;
            const int d0 = q * 8;
            float a[8], b[8];
            #pragma unroll
            for (int j = 0; j < 8; ++j) {
                a[j] = c1[(long)(d0 + j) * NN];
                b[j] = c2[(long)(d0 + j) * NN];
            }
            union { __hip_bfloat162 h[4]; bf16x8 v; } pa, pb;
            #pragma unroll
            for (int j = 0; j < 4; ++j) {
                pa.h[j] = __float22bfloat162_rn(make_float2(a[2*j], a[2*j+1]));
                pb.h[j] = __float22bfloat162_rn(make_float2(b[2*j], b[2*j+1]));
            }
            const int off = (q ^ (il & 15)) << 4;
            *(bf16x8*)(r1 + off) = pa.v;
            *(bf16x8*)(r2 + off) = pb.v;
        }
    }
    __syncthreads();
    const int lane = t & 63;
    const int wid  = t >> 6;
    const int wr   = wid >> 1, wc = wid & 1;
    const int l15  = lane & 15, l4 = lane >> 4;
    float sreg[4][4][4];
    #pragma unroll
    for (int am = 0; am < 4; ++am)
        #pragma unroll
        for (int r = 0; r < 4; ++r) {
            const long gi    = (long)(i0 + wr * 64 + am * 16 + l4 * 4 + r);
            const long basep = gi * NN + j0 + wc * 64 + l15;
            #pragma unroll
            for (int bn = 0; bn < 4; ++bn)
                sreg[am][bn][r] = S[basep + bn * 16];
        }
    f32x4 acc[4][4] = {};
    #pragma unroll
    for (int kb = 0; kb < 4; ++kb) {
        bf16x8 afl[4], bgr[4];
        #pragma unroll
        for (int m = 0; m < 4; ++m) {
            const int ia = wr * 64 + m * 16 + l15;
            afl[m] = *(const bf16x8*)(lds[0] + ia * 256 + (((kb * 4 + l4) ^ l15) << 4));
            const int jbq = wc * 64 + m * 16 + l15;
            bgr[m] = *(const bf16x8*)(lds[1] + jbq * 256 + (((kb * 4 + l4) ^ l15) << 4));
        }
        #pragma unroll
        for (int m = 0; m < 4; ++m)
            #pragma unroll
            for (int n = 0; n < 4; ++n)
                acc[m][n] = __builtin_amdgcn_mfma_f32_16x16x32_bf16(afl[m], bgr[n], acc[m][n], 0, 0, 0);
    }
    float lsum = 0.f;
    #pragma unroll
    for (int m = 0; m < 4; ++m)
        #pragma unroll
        for (int n = 0; n < 4; ++n)
            #pragma unroll
            for (int r = 0; r < 4; ++r) {
                const float o = 0.5f * acc[m][n][r];
                lsum += fmaf(-sreg[m][n][r], o, __logf(1.0f + o + eps));
            }
    float v = lsum;
    #pragma unroll
    for (int off = 32; off; off >>= 1) v += __shfl_down(v, off);
    if ((t & 63) == 0) red[t >> 6] = v;
    __syncthreads();
    if (t == 0) {
        const float tot = red[0] + red[1] + red[2] + red[3];
        atomicAdd(accum, (double)tot);   // slot 0
    }
}

// ---------------- small kernels ----------------
__global__ __launch_bounds__(256)
void bqc_kernel(const float* __restrict__ FP, const float* __restrict__ FM,
                const float* __restrict__ B, double* __restrict__ ws)
{
    __shared__ float red1[4], red2[4];
    const int n4 = DD * NN / 4;
    float s1 = 0.f, s2 = 0.f;
    for (int i = blockIdx.x * blockDim.x + threadIdx.x; i < n4;
         i += gridDim.x * blockDim.x) {
        const float4 p = ((const float4*)FP)[i];
        const float4 m = ((const float4*)FM)[i];
        const float4 b = ((const float4*)B)[i];
        float d;
        d = p.x - b.x; s1 += d * d;  d = p.y - b.y; s1 += d * d;
        d = p.z - b.z; s1 += d * d;  d = p.w - b.w; s1 += d * d;
        d = m.x - b.x; s2 += d * d;  d = m.y - b.y; s2 += d * d;
        d = m.z - b.z; s2 += d * d;  d = m.w - b.w; s2 += d * d;
    }
    const int t = threadIdx.x;
    #pragma unroll
    for (int off = 32; off; off >>= 1) {
        s1 += __shfl_down(s1, off);
        s2 += __shfl_down(s2, off);
    }
    if ((t & 63) == 0) { red1[t >> 6] = s1; red2[t >> 6] = s2; }
    __syncthreads();
    if (t == 0) {
        atomicAdd(&ws[128], (double)(red1[0] + red1[1] + red1[2] + red1[3]));
        atomicAdd(&ws[129], (double)(red2[0] + red2[1] + red2[2] + red2[3]));
    }
}

__global__ __launch_bounds__(256)
void fdc_kernel(const float* __restrict__ FP, const float* __restrict__ FM,
                double* __restrict__ ws)
{
    __shared__ float red[4];
    const float* F = (blockIdx.x >= DD) ? FM : FP;
    const int row = blockIdx.x & (DD - 1);
    float s = 0.f;
    const float4* rowp = (const float4*)&F[(long)row * NN];
    for (int i = threadIdx.x; i < NN / 4; i += blockDim.x) {
        const float4 v = rowp[i];
        s += v.x + v.y + v.z + v.w;
    }
    const int t = threadIdx.x;
    #pragma unroll
    for (int off = 32; off; off >>= 1) s += __shfl_down(s, off);
    if ((t & 63) == 0) red[t >> 6] = s;
    __syncthreads();
    if (t == 0) {
        const double rs = (double)(red[0] + red[1] + red[2] + red[3]);
        atomicAdd(&ws[130], rs * rs);
    }
}

__global__ void finalize_kernel(const double* __restrict__ ws, float* __restrict__ out)
{
    if (threadIdx.x == 0 && blockIdx.x == 0) {
        double s = 0.0;
        #pragma unroll
        for (int k = 0; k < 16; ++k) s += ws[k * 8];
        out[0] = (float)(s + ws[130] + sqrt(ws[128]) + sqrt(ws[129]));
    }
}

extern "C" void kernel_launch(void* const* d_in, const int* in_sizes, int n_in,
                              void* d_out, int out_size, void* d_ws, size_t ws_size,
                              hipStream_t stream)
{
    const float* SU = (const float*)d_in[0];
    const float* SP = (const float*)d_in[1];
    const float* SM = (const float*)d_in[2];
    const float* FP = (const float*)d_in[3];
    const float* FM = (const float*)d_in[4];
    const float* B  = (const float*)d_in[5];
    float*  out = (float*)d_out;
    double* ws  = (double*)d_ws;

    hipMemsetAsync(d_ws, 0, 4096, stream);

    const size_t fb   = (size_t)NN * DD * sizeof(__hip_bfloat16);   // 1 MB
    const size_t need = 4096 + 2 * fb;

    if (ws_size >= need) {
        char* base = (char*)d_ws + 4096;
        __hip_bfloat16* FPt = (__hip_bfloat16*)(base);
        __hip_bfloat16* FMt = (__hip_bfloat16*)(base + fb);
        convert_bqc_kernel<<<dim3(NN / 128, 2), 256, 0, stream>>>(FP, FM, B, FPt, FMt, ws);
        gemm_loss_pc<<<768, 512, 0, stream>>>(SU, SP, SM, FPt, FMt, ws);
        fdc_kernel<<<256, 256, 0, stream>>>(FP, FM, ws);
    } else {
        dim3 grid(NN / 128, NN / 128);
        gemm_loss_mfma<<<grid, 256, 0, stream>>>(SU, FP, FM, 0.0f, ws);
        gemm_loss_mfma<<<grid, 256, 0, stream>>>(SP, FP, FP, 1e-8f, ws);
        gemm_loss_mfma<<<grid, 256, 0, stream>>>(SM, FM, FM, 1e-8f, ws);
        bqc_kernel<<<512, 256, 0, stream>>>(FP, FM, B, ws);
        fdc_kernel<<<256, 256, 0, stream>>>(FP, FM, ws);
    }
    finalize_kernel<<<1, 64, 0, stream>>>(ws, out);
}

// Round 15
// 159.930 us; speedup vs baseline: 1.1520x; 1.1520x over previous
//
#include <hip/hip_runtime.h>
#include <hip/hip_bf16.h>
#include <math.h>

#define NN 4096
#define DD 128

typedef __attribute__((ext_vector_type(8))) short bf16x8;
typedef __attribute__((ext_vector_type(4))) float f32x4;
#define AS3 __attribute__((address_space(3)))

// ws layout (doubles): gemm-loss slots ws[k*8], k=0..15; ws[128]=bqc1,
// ws[129]=bqc2, ws[130]=fdc. Then FPt/FMt bf16 (2MB), then Omega bf16 (100MB).

__device__ __forceinline__ void gload_lds16(const float* g, float* l) {
    __builtin_amdgcn_global_load_lds((const __attribute__((address_space(1))) char*)g,
                                     (AS3 char*)l, 16, 0, 0);
}

// ---- fused prep: convert F (f32 [d][i]) -> bf16 [i][d]  +  bqc partials ----
__global__ __launch_bounds__(256)
void convert_bqc_kernel(const float* __restrict__ FP, const float* __restrict__ FM,
                        const float* __restrict__ B,
                        __hip_bfloat16* __restrict__ FPt, __hip_bfloat16* __restrict__ FMt,
                        double* __restrict__ ws)
{
    const int y = blockIdx.y;
    const float* src = y ? FM : FP;
    __hip_bfloat16* dst = y ? FMt : FPt;
    const int t  = threadIdx.x;
    const int il = t & 127;
    const int dh = t >> 7;
    const int i  = blockIdx.x * 128 + il;
    float s = 0.f;
    #pragma unroll
    for (int it = 0; it < 8; ++it) {
        const int d0 = dh * 64 + it * 8;
        float a[8];
        #pragma unroll
        for (int j = 0; j < 8; ++j) {
            a[j] = src[(long)(d0 + j) * NN + i];
            const float b = B[(long)(d0 + j) * NN + i];
            const float d = a[j] - b;
            s += d * d;
        }
        union { __hip_bfloat162 h[4]; bf16x8 v; } p;
        #pragma unroll
        for (int j = 0; j < 4; ++j)
            p.h[j] = __float22bfloat162_rn(make_float2(a[2*j], a[2*j+1]));
        *(bf16x8*)&dst[(long)i * DD + d0] = p.v;
    }
    __shared__ float red[4];
    #pragma unroll
    for (int off = 32; off; off >>= 1) s += __shfl_down(s, off);
    if ((t & 63) == 0) red[t >> 6] = s;
    __syncthreads();
    if (t == 0)
        atomicAdd(&ws[128 + y], (double)(red[0] + red[1] + red[2] + red[3]));
}

// ---- phase 1: Omega_z = 0.5 * Fa^T Fb, written bf16 row-major -------------
// 128x128 tile, 4 waves = 2x2 of 64x64. SWAPPED operands (r11-verified):
// acc[m][n] = mfma(bj[n], ai[m]) -> lane holds i = i0+m*16+l15 (col),
// j = j0+n*16+l4*4+r (row, 4 consecutive) -> one 8B packed store per (m,n).
__global__ __launch_bounds__(256, 2)
void omega_kernel(const __hip_bfloat16* __restrict__ FPt_,
                  const __hip_bfloat16* __restrict__ FMt_,
                  __hip_bfloat16* __restrict__ Om_)
{
    const int t = threadIdx.x;
    const int lane = t & 63, wid = t >> 6;
    const int wr = wid >> 1, wc = wid & 1;
    const int l15 = lane & 15, l4 = lane >> 4;
    const int z  = blockIdx.z;
    const int i0 = blockIdx.y * 128 + wr * 64;
    const int j0 = blockIdx.x * 128 + wc * 64;
    const short* Fi = (const short*)((z == 2) ? FMt_ : FPt_);
    const short* Fj = (const short*)((z == 0) ? FMt_ : (z == 1) ? FPt_ : FMt_);
    unsigned short* Om = (unsigned short*)Om_ + (long)z * NN * NN;

    bf16x8 ai[4][4], bj[4][4];
    #pragma unroll
    for (int m = 0; m < 4; ++m)
        #pragma unroll
        for (int kb = 0; kb < 4; ++kb) {
            ai[m][kb] = *(const bf16x8*)&Fi[(long)(i0 + m * 16 + l15) * DD + kb * 32 + l4 * 8];
            bj[m][kb] = *(const bf16x8*)&Fj[(long)(j0 + m * 16 + l15) * DD + kb * 32 + l4 * 8];
        }
    f32x4 acc[4][4] = {};
    #pragma unroll
    for (int kb = 0; kb < 4; ++kb)
        #pragma unroll
        for (int m = 0; m < 4; ++m)
            #pragma unroll
            for (int n = 0; n < 4; ++n)
                acc[m][n] = __builtin_amdgcn_mfma_f32_16x16x32_bf16(bj[n][kb], ai[m][kb], acc[m][n], 0, 0, 0);
    #pragma unroll
    for (int m = 0; m < 4; ++m)
        #pragma unroll
        for (int n = 0; n < 4; ++n) {
            union { __hip_bfloat162 h[2]; uint2 u; } p;
            p.h[0] = __float22bfloat162_rn(make_float2(0.5f * acc[m][n][0], 0.5f * acc[m][n][1]));
            p.h[1] = __float22bfloat162_rn(make_float2(0.5f * acc[m][n][2], 0.5f * acc[m][n][3]));
            *(uint2*)&Om[(long)(i0 + m * 16 + l15) * NN + j0 + n * 16 + l4 * 4] = p.u;
        }
}

// ---- phase 2: pure grid-stride linear consume ------------------------------
// Per thread-iter: 32B of S (2x float4) + 16B of Omega (uint4 = 8 bf16);
// -S*w + log(w + onep); structurally identical to the 6.3 TB/s copy ubench.
__global__ __launch_bounds__(256)
void consume_kernel(const float* __restrict__ SU, const float* __restrict__ SP,
                    const float* __restrict__ SM,
                    const __hip_bfloat16* __restrict__ Om_,
                    double* __restrict__ accum)
{
    const unsigned* Om = (const unsigned*)Om_;
    const long seg = (long)NN * NN / 8;          // 2^21 (8-elem units)
    float lsum = 0.f;
    const long step = (long)gridDim.x * 256;
    for (long e = blockIdx.x * 256 + threadIdx.x; e < 3 * seg; e += step) {
        const int z = (int)(e >> 21);
        const long off = e & (seg - 1);
        const float* Sp = ((z == 0) ? SU : (z == 1) ? SP : SM) + off * 8;
        const float onep = (z == 0) ? 1.0f : 1.0f + 1e-8f;
        const float4 s0 = *(const float4*)Sp;
        const float4 s1 = *(const float4*)(Sp + 4);
        const uint4 q = *(const uint4*)&Om[(long)z * ((long)NN * NN / 2) + off * 4];
#define TERM(w, slo, shi)                                                      \
        {                                                                      \
            const float o0 = __uint_as_float((w) << 16);                       \
            const float o1 = __uint_as_float((w) & 0xFFFF0000u);               \
            lsum += fmaf(-(slo), o0, __logf(o0 + onep));                       \
            lsum += fmaf(-(shi), o1, __logf(o1 + onep));                       \
        }
        TERM(q.x, s0.x, s0.y)
        TERM(q.y, s0.z, s0.w)
        TERM(q.z, s1.x, s1.y)
        TERM(q.w, s1.z, s1.w)
#undef TERM
    }
    float v = lsum;
    #pragma unroll
    for (int off = 32; off; off >>= 1) v += __shfl_down(v, off);
    if ((threadIdx.x & 63) == 0)
        atomicAdd(accum + ((blockIdx.x & 15) << 3), (double)v);
}

// ---- mid-fallback: round-7 fused kernel (92.6 us path) --------------------
__global__ __launch_bounds__(256, 2)
void gemm_loss_fused(const float* __restrict__ SU, const float* __restrict__ SP,
                     const float* __restrict__ SM,
                     const __hip_bfloat16* __restrict__ FPt_,
                     const __hip_bfloat16* __restrict__ FMt_,
                     double* __restrict__ accum)
{
    __shared__ float sS[4][2][32 * 32];
    const int t0   = threadIdx.x;
    const int lane = t0 & 63, wid = t0 >> 6;
    const int l15  = lane & 15, l4 = lane >> 4;
    const int w    = blockIdx.x * 4 + wid;
    const int jt   = w & 127, rr = w >> 7;
    const int j0   = jt * 32;
    const short* FPt = (const short*)FPt_;
    const short* FMt = (const short*)FMt_;

    bf16x8 bgP[2][4], bgM[2][4];
    #pragma unroll
    for (int n = 0; n < 2; ++n)
        #pragma unroll
        for (int kb = 0; kb < 4; ++kb) {
            const long off = (long)(j0 + n * 16 + l15) * DD + kb * 32 + l4 * 8;
            bgP[n][kb] = *(const bf16x8*)&FPt[off];
            bgM[n][kb] = *(const bf16x8*)&FMt[off];
        }

    float lsum = 0.f;
    bf16x8 afA[2][4], afB[2][4];

#define TILE_Z(tt)   ((tt) >> 3)
#define TILE_I0(tt)  ((rr + (((tt) & 7) << 4)) << 5)
#define ISSUE_AF(tt, dstbuf)                                                   \
    {                                                                          \
        const int z_  = TILE_Z(tt);                                            \
        const int i0_ = TILE_I0(tt);                                           \
        const short* Fa_ = (z_ == 2) ? FMt : FPt;                              \
        _Pragma("unroll")                                                      \
        for (int m = 0; m < 2; ++m)                                            \
            _Pragma("unroll")                                                  \
            for (int kb = 0; kb < 4; ++kb)                                     \
                dstbuf[m][kb] = *(const bf16x8*)&Fa_[(long)(i0_ + m * 16 + l15) * DD + kb * 32 + l4 * 8]; \
    }
#define ISSUE_STAGE(tt)                                                        \
    {                                                                          \
        const int z_  = TILE_Z(tt);                                            \
        const int i0_ = TILE_I0(tt);                                           \
        const float* S_ = (z_ == 0) ? SU : (z_ == 1) ? SP : SM;                \
        const float* src_ = S_ + (long)(i0_ + (lane >> 3)) * NN + j0 + (lane & 7) * 4; \
        float* dst_ = &sS[wid][(tt) & 1][0];                                   \
        _Pragma("unroll")                                                      \
        for (int q_ = 0; q_ < 4; ++q_)                                         \
            gload_lds16(src_ + (long)q_ * 8 * NN, dst_ + q_ * 256);            \
    }
#define TILE_BODY(tt, cur, nxt)                                                \
    {                                                                          \
        const int tc = (tt);                                                   \
        const int tn = (tc < 23) ? tc + 1 : 23;                                \
        ISSUE_AF(tn, nxt);                                                     \
        __builtin_amdgcn_sched_barrier(0);                                     \
        ISSUE_STAGE(tn);                                                       \
        __builtin_amdgcn_sched_barrier(0);                                     \
        asm volatile("s_waitcnt vmcnt(12)");                                   \
        __builtin_amdgcn_sched_barrier(0);                                     \
        const int z_  = TILE_Z(tc);                                            \
        f32x4 acc[2][2] = {};                                                  \
        if (z_ == 1) {                                                         \
            _Pragma("unroll")                                                  \
            for (int kb = 0; kb < 4; ++kb)                                     \
                _Pragma("unroll")                                              \
                for (int m = 0; m < 2; ++m)                                    \
                    _Pragma("unroll")                                          \
                    for (int n = 0; n < 2; ++n)                                \
                        acc[m][n] = __builtin_amdgcn_mfma_f32_16x16x32_bf16(cur[m][kb], bgP[n][kb], acc[m][n], 0, 0, 0); \
        } else {                                                               \
            _Pragma("unroll")                                                  \
            for (int kb = 0; kb < 4; ++kb)                                     \
                _Pragma("unroll")                                              \
                for (int m = 0; m < 2; ++m)                                    \
                    _Pragma("unroll")                                          \
                    for (int n = 0; n < 2; ++n)                                \
                        acc[m][n] = __builtin_amdgcn_mfma_f32_16x16x32_bf16(cur[m][kb], bgM[n][kb], acc[m][n], 0, 0, 0); \
        }                                                                      \
        const float onep = (z_ == 0) ? 1.0f : 1.0f + 1e-8f;                    \
        const float* q = &sS[wid][tc & 1][0];                                  \
        _Pragma("unroll")                                                      \
        for (int m = 0; m < 2; ++m)                                            \
            _Pragma("unroll")                                                  \
            for (int n = 0; n < 2; ++n)                                        \
                _Pragma("unroll")                                              \
                for (int r = 0; r < 4; ++r) {                                  \
                    const float s = q[(m * 16 + l4 * 4 + r) * 32 + n * 16 + l15]; \
                    const float o = 0.5f * acc[m][n][r];                       \
                    lsum += fmaf(-s, o, __logf(o + onep));                     \
                }                                                              \
    }

    ISSUE_AF(0, afA);
    ISSUE_STAGE(0);
    #pragma unroll 1
    for (int t = 0; t < 24; t += 2) {
        TILE_BODY(t,     afA, afB);
        TILE_BODY(t + 1, afB, afA);
    }
#undef TILE_BODY
#undef ISSUE_STAGE
#undef ISSUE_AF
#undef TILE_Z
#undef TILE_I0

    float v = lsum;
    #pragma unroll
    for (int off = 32; off; off >>= 1) v += __shfl_down(v, off);
    if (lane == 0)
        atomicAdd(accum + ((w & 15) << 3), (double)v);
}

// ---------------- deep fallback (round-2 kernel) ----------------------------
__global__ __launch_bounds__(256, 2)
void gemm_loss_mfma(const float* __restrict__ S, const float* __restrict__ F1,
                    const float* __restrict__ F2, float eps, double* __restrict__ accum)
{
    __shared__ char lds[2][128 * 256];
    __shared__ float red[4];
    const int t  = threadIdx.x;
    const int i0 = blockIdx.y * 128;
    const int j0 = blockIdx.x * 128;
    {
        const int il   = t & 127;
        const int half = t >> 7;
        const float* c1 = F1 + i0 + il;
        const float* c2 = F2 + j0 + il;
        char* r1 = lds[0] + il * 256;
        char* r2 = lds[1] + il * 256;
        #pragma unroll
        for (int it = 0; it < 8; ++it) {
            const int q  = half * 8 + it;
            const int d0 = q * 8;
            float a[8], b[8];
            #pragma unroll
            for (int j = 0; j < 8; ++j) {
                a[j] = c1[(long)(d0 + j) * NN];
                b[j] = c2[(long)(d0 + j) * NN];
            }
            union { __hip_bfloat162 h[4]; bf16x8 v; } pa, pb;
            #pragma unroll
            for (int j = 0; j < 4; ++j) {
                pa.h[j] = __float22bfloat162_rn(make_float2(a[2*j], a[2*j+1]));
                pb.h[j] = __float22bfloat162_rn(make_float2(b[2*j], b[2*j+1]));
            }
            const int off = (q ^ (il & 15)) << 4;
            *(bf16x8*)(r1 + off) = pa.v;
            *(bf16x8*)(r2 + off) = pb.v;
        }
    }
    __syncthreads();
    const int lane = t & 63;
    const int wid  = t >> 6;
    const int wr   = wid >> 1, wc = wid & 1;
    const int l15  = lane & 15, l4 = lane >> 4;
    float sreg[4][4][4];
    #pragma unroll
    for (int am = 0; am < 4; ++am)
        #pragma unroll
        for (int r = 0; r < 4; ++r) {
            const long gi    = (long)(i0 + wr * 64 + am * 16 + l4 * 4 + r);
            const long basep = gi * NN + j0 + wc * 64 + l15;
            #pragma unroll
            for (int bn = 0; bn < 4; ++bn)
                sreg[am][bn][r] = S[basep + bn * 16];
        }
    f32x4 acc[4][4] = {};
    #pragma unroll
    for (int kb = 0; kb < 4; ++kb) {
        bf16x8 afl[4], bgr[4];
        #pragma unroll
        for (int m = 0; m < 4; ++m) {
            const int ia = wr * 64 + m * 16 + l15;
            afl[m] = *(const bf16x8*)(lds[0] + ia * 256 + (((kb * 4 + l4) ^ l15) << 4));
            const int jbq = wc * 64 + m * 16 + l15;
            bgr[m] = *(const bf16x8*)(lds[1] + jbq * 256 + (((kb * 4 + l4) ^ l15) << 4));
        }
        #pragma unroll
        for (int m = 0; m < 4; ++m)
            #pragma unroll
            for (int n = 0; n < 4; ++n)
                acc[m][n] = __builtin_amdgcn_mfma_f32_16x16x32_bf16(afl[m], bgr[n], acc[m][n], 0, 0, 0);
    }
    float lsum = 0.f;
    #pragma unroll
    for (int m = 0; m < 4; ++m)
        #pragma unroll
        for (int n = 0; n < 4; ++n)
            #pragma unroll
            for (int r = 0; r < 4; ++r) {
                const float o = 0.5f * acc[m][n][r];
                lsum += fmaf(-sreg[m][n][r], o, __logf(1.0f + o + eps));
            }
    float v = lsum;
    #pragma unroll
    for (int off = 32; off; off >>= 1) v += __shfl_down(v, off);
    if ((t & 63) == 0) red[t >> 6] = v;
    __syncthreads();
    if (t == 0) {
        const float tot = red[0] + red[1] + red[2] + red[3];
        atomicAdd(accum, (double)tot);
    }
}

// ---------------- small kernels ----------------
__global__ __launch_bounds__(256)
void bqc_kernel(const float* __restrict__ FP, const float* __restrict__ FM,
                const float* __restrict__ B, double* __restrict__ ws)
{
    __shared__ float red1[4], red2[4];
    const int n4 = DD * NN / 4;
    float s1 = 0.f, s2 = 0.f;
    for (int i = blockIdx.x * blockDim.x + threadIdx.x; i < n4;
         i += gridDim.x * blockDim.x) {
        const float4 p = ((const float4*)FP)[i];
        const float4 m = ((const float4*)FM)[i];
        const float4 b = ((const float4*)B)[i];
        float d;
        d = p.x - b.x; s1 += d * d;  d = p.y - b.y; s1 += d * d;
        d = p.z - b.z; s1 += d * d;  d = p.w - b.w; s1 += d * d;
        d = m.x - b.x; s2 += d * d;  d = m.y - b.y; s2 += d * d;
        d = m.z - b.z; s2 += d * d;  d = m.w - b.w; s2 += d * d;
    }
    const int t = threadIdx.x;
    #pragma unroll
    for (int off = 32; off; off >>= 1) {
        s1 += __shfl_down(s1, off);
        s2 += __shfl_down(s2, off);
    }
    if ((t & 63) == 0) { red1[t >> 6] = s1; red2[t >> 6] = s2; }
    __syncthreads();
    if (t == 0) {
        atomicAdd(&ws[128], (double)(red1[0] + red1[1] + red1[2] + red1[3]));
        atomicAdd(&ws[129], (double)(red2[0] + red2[1] + red2[2] + red2[3]));
    }
}

__global__ __launch_bounds__(256)
void fdc_kernel(const float* __restrict__ FP, const float* __restrict__ FM,
                double* __restrict__ ws)
{
    __shared__ float red[4];
    const float* F = (blockIdx.x >= DD) ? FM : FP;
    const int row = blockIdx.x & (DD - 1);
    float s = 0.f;
    const float4* rowp = (const float4*)&F[(long)row * NN];
    for (int i = threadIdx.x; i < NN / 4; i += blockDim.x) {
        const float4 v = rowp[i];
        s += v.x + v.y + v.z + v.w;
    }
    const int t = threadIdx.x;
    #pragma unroll
    for (int off = 32; off; off >>= 1) s += __shfl_down(s, off);
    if ((t & 63) == 0) red[t >> 6] = s;
    __syncthreads();
    if (t == 0) {
        const double rs = (double)(red[0] + red[1] + red[2] + red[3]);
        atomicAdd(&ws[130], rs * rs);
    }
}

__global__ void finalize_kernel(const double* __restrict__ ws, float* __restrict__ out)
{
    if (threadIdx.x == 0 && blockIdx.x == 0) {
        double s = 0.0;
        #pragma unroll
        for (int k = 0; k < 16; ++k) s += ws[k * 8];
        out[0] = (float)(s + ws[130] + sqrt(ws[128]) + sqrt(ws[129]));
    }
}

extern "C" void kernel_launch(void* const* d_in, const int* in_sizes, int n_in,
                              void* d_out, int out_size, void* d_ws, size_t ws_size,
                              hipStream_t stream)
{
    const float* SU = (const float*)d_in[0];
    const float* SP = (const float*)d_in[1];
    const float* SM = (const float*)d_in[2];
    const float* FP = (const float*)d_in[3];
    const float* FM = (const float*)d_in[4];
    const float* B  = (const float*)d_in[5];
    float*  out = (float*)d_out;
    double* ws  = (double*)d_ws;

    hipMemsetAsync(d_ws, 0, 4096, stream);

    const size_t fb       = (size_t)NN * DD * sizeof(__hip_bfloat16);      // 1 MB
    const size_t om_bytes = (size_t)3 * NN * NN * sizeof(__hip_bfloat16);  // 100.7 MB
    const size_t need_sm  = 4096 + 2 * fb;
    const size_t need_big = need_sm + om_bytes;

    if (ws_size >= need_sm) {
        char* base = (char*)d_ws + 4096;
        __hip_bfloat16* FPt = (__hip_bfloat16*)(base);
        __hip_bfloat16* FMt = (__hip_bfloat16*)(base + fb);
        convert_bqc_kernel<<<dim3(NN / 128, 2), 256, 0, stream>>>(FP, FM, B, FPt, FMt, ws);
        if (ws_size >= need_big) {
            __hip_bfloat16* Om = (__hip_bfloat16*)(base + 2 * fb);
            omega_kernel<<<dim3(NN / 128, NN / 128, 3), 256, 0, stream>>>(FPt, FMt, Om);
            consume_kernel<<<2048, 256, 0, stream>>>(SU, SP, SM, Om, ws);
        } else {
            gemm_loss_fused<<<512, 256, 0, stream>>>(SU, SP, SM, FPt, FMt, ws);
        }
        fdc_kernel<<<256, 256, 0, stream>>>(FP, FM, ws);
    } else {
        dim3 grid(NN / 128, NN / 128);
        gemm_loss_mfma<<<grid, 256, 0, stream>>>(SU, FP, FM, 0.0f, ws);
        gemm_loss_mfma<<<grid, 256, 0, stream>>>(SP, FP, FP, 1e-8f, ws);
        gemm_loss_mfma<<<grid, 256, 0, stream>>>(SM, FM, FM, 1e-8f, ws);
        bqc_kernel<<<512, 256, 0, stream>>>(FP, FM, B, ws);
        fdc_kernel<<<256, 256, 0, stream>>>(FP, FM, ws);
    }
    finalize_kernel<<<1, 64, 0, stream>>>(ws, out);
}